// Round 4
// baseline (598.583 us; speedup 1.0000x reference)
//
#include <hip/hip_runtime.h>

constexpr int DIM = 96;
constexpr int HW  = DIM * DIM;            // 9216
constexpr int DHW = DIM * DIM * DIM;      // 884736
constexpr int NC  = 64;
constexpr int NK  = 27;

// Tile: 4(z) x 8(y) x 16(x) outputs per block, 2 outputs/thread in x (R3 geometry).
constexpr int TZ = 4, TY = 8, TX = 16;
constexpr int LY = TY + 2;                // 10
constexpr int LXP = 20;                   // 18 live + 2 pad words per row
constexpr int NSTG = 5;                   // 5 dword DMA / thread / channel
constexpr int LDSN = NSTG * 256;          // 1280 words per buffer

typedef const __attribute__((address_space(1))) unsigned int* gas_ptr;
typedef __attribute__((address_space(3))) unsigned int* las_ptr;

__global__ __launch_bounds__(256, 6)
void wincorr_kernel(const float* __restrict__ fixed_,
                    const float* __restrict__ moving,
                    float* __restrict__ out)
{
    // Triple buffer: channel c lives in sm[c % 3]. 15.4 KB total.
    __shared__ __align__(16) float sm[3][LDSN];

    const int tid = threadIdx.x;
    const int tx = tid & 7;          // 8 x-chunks of 2
    const int ty = (tid >> 3) & 7;   // 8 y
    const int tz = tid >> 6;         // 4 z (wave id)
    const int bx0 = blockIdx.x * TX;
    const int by0 = blockIdx.y * TY;
    const int bz0 = blockIdx.z * TZ;

    // Channel-invariant staging source offsets (edge clamp here). LDS dest is
    // forced linear (global_load_lds writes base + lane*4), layout [lz][ly][LXP].
    int g_off[NSTG];
#pragma unroll
    for (int i = 0; i < NSTG; ++i) {
        const int t  = tid + i * 256;
        const int lz = t / (LY * LXP);
        const int r  = t - lz * (LY * LXP);
        const int ly = r / LXP;
        const int lx = r - ly * LXP;            // lx 18,19 + tail = dummies (never read)
        const int gz = min(max(bz0 - 1 + lz, 0), DIM - 1);
        const int gy = min(max(by0 - 1 + ly, 0), DIM - 1);
        const int gx = min(max(bx0 - 1 + lx, 0), DIM - 1);
        g_off[i] = gz * HW + gy * DIM + gx;
    }

    const int z = bz0 + tz, y = by0 + ty, x0 = bx0 + 2 * tx;
    const int foff = z * HW + y * DIM + x0;

    float acc[NK][2];
#pragma unroll
    for (int k = 0; k < NK; ++k) { acc[k][0] = 0.f; acc[k][1] = 0.f; }

    // ---- Prologue: stage ch0 AND ch1, wait only for ch0 ----
    // Queue after issue (oldest->newest): stage0 x5, stage1 x5, pf x1.
    // vmcnt(5) => everything older than the newest 5 done => stage0 landed.
#pragma unroll
    for (int i = 0; i < NSTG; ++i)
        __builtin_amdgcn_global_load_lds((gas_ptr)(moving + g_off[i]),
                                         (las_ptr)&sm[0][tid + i * 256], 4, 0, 0);
#pragma unroll
    for (int i = 0; i < NSTG; ++i)
        __builtin_amdgcn_global_load_lds((gas_ptr)(moving + DHW + g_off[i]),
                                         (las_ptr)&sm[1][tid + i * 256], 4, 0, 0);
    float2 pf = *(const float2*)(fixed_ + foff);
    asm volatile("s_waitcnt vmcnt(5)" ::: "memory");
    __builtin_amdgcn_s_barrier();

    const int rb = 2 * tx;                       // even word -> 8B-aligned reads

    for (int c = 0; c < NC; ++c) {
        const float* buf = sm[c % 3];

        // Issue DMA two channels ahead into sm[(c+2)%3] (last read at iter c-1,
        // protected by the previous lgkmcnt(0)+barrier). It has ~2 channel-times
        // to land -- never drained early.
        if (c + 2 < NC) {
            const float* mc = moving + (size_t)(c + 2) * DHW;
            float* dst = sm[(c + 2) % 3];
#pragma unroll
            for (int i = 0; i < NSTG; ++i)
                __builtin_amdgcn_global_load_lds((gas_ptr)(mc + g_off[i]),
                                                 (las_ptr)&dst[tid + i * 256], 4, 0, 0);
        }
        const float2 fv = pf;
        if (c + 1 < NC)
            pf = *(const float2*)(fixed_ + (size_t)(c + 1) * DHW + foff);

#pragma unroll
        for (int dz = 0; dz < 3; ++dz)
#pragma unroll
        for (int dy = 0; dy < 3; ++dy) {
            const float* row = buf + ((tz + dz) * LY + (ty + dy)) * LXP + rb;
            const float2 a = *(const float2*)row;        // words 2tx,2tx+1
            const float2 b = *(const float2*)(row + 2);  // words 2tx+2,2tx+3
            const int kb = (dz * 3 + dy) * 3;
            acc[kb + 0][0] += fv.x * a.x;  acc[kb + 0][1] += fv.y * a.y;
            acc[kb + 1][0] += fv.x * a.y;  acc[kb + 1][1] += fv.y * b.x;
            acc[kb + 2][0] += fv.x * b.x;  acc[kb + 2][1] += fv.y * b.y;
        }

        // Counted wait, NOT vmcnt(0): ops newer than stage(c+1) are exactly
        // stage(c+2) [5] + pf(c+1) [1] = 6. lgkmcnt(0) retires this iter's
        // ds_reads before the barrier releases the buffer for DMA overwrite.
        if (c + 1 < NC) {
            if (c + 2 < NC)
                asm volatile("s_waitcnt vmcnt(6) lgkmcnt(0)" ::: "memory");
            else
                asm volatile("s_waitcnt vmcnt(0) lgkmcnt(0)" ::: "memory");
            __builtin_amdgcn_s_barrier();
        }
    }

    // Epilogue: scale by 64^-0.5 = 0.125, 8B coalesced stores
#pragma unroll
    for (int k = 0; k < NK; ++k) {
        float2 o;
        o.x = acc[k][0] * 0.125f;
        o.y = acc[k][1] * 0.125f;
        *(float2*)(out + (size_t)k * DHW + foff) = o;
    }
}

extern "C" void kernel_launch(void* const* d_in, const int* in_sizes, int n_in,
                              void* d_out, int out_size, void* d_ws, size_t ws_size,
                              hipStream_t stream) {
    const float* fixed_  = (const float*)d_in[0];
    const float* moving  = (const float*)d_in[1];
    float* out = (float*)d_out;
    dim3 grid(DIM / TX, DIM / TY, DIM / TZ);   // 6 x 12 x 24 = 1728 blocks
    dim3 block(256);
    wincorr_kernel<<<grid, block, 0, stream>>>(fixed_, moving, out);
}